// Round 1
// baseline (80.487 us; speedup 1.0000x reference)
//
#include <hip/hip_runtime.h>

#define BB 16
#define LL 2048
#define DD 256

// K1: sk[row] = dot(inp[row,:], wk)  — one wave (64 lanes) per row, float4/lane
__global__ void k1_sk(const float* __restrict__ inp, const float* __restrict__ wk,
                      float* __restrict__ sk) {
    int tid  = threadIdx.x;
    int wid  = tid >> 6, lane = tid & 63;
    int row  = blockIdx.x * 4 + wid;              // 8192 blocks * 4 waves = 32768 rows
    const float4 a = *reinterpret_cast<const float4*>(inp + (size_t)row * DD + lane * 4);
    const float4 w = *reinterpret_cast<const float4*>(wk + lane * 4);
    float dot = a.x * w.x + a.y * w.y + a.z * w.z + a.w * w.w;
    #pragma unroll
    for (int off = 32; off >= 1; off >>= 1) dot += __shfl_down(dot, off, 64);
    if (lane == 0) sk[row] = dot;
}

// K2: per-batch softmax over L values -> p[b,j]
__global__ void k2_softmax(const float* __restrict__ sk, float* __restrict__ p) {
    int b = blockIdx.x;
    int tid = threadIdx.x;
    int lane = tid & 63, wid = tid >> 6;
    const float* skb = sk + b * LL;
    float v[8];
    #pragma unroll
    for (int r = 0; r < 8; ++r) v[r] = skb[tid + r * 256];
    float mx = v[0];
    #pragma unroll
    for (int r = 1; r < 8; ++r) mx = fmaxf(mx, v[r]);
    __shared__ float sm[4];
    __shared__ float bc;
    #pragma unroll
    for (int off = 32; off >= 1; off >>= 1) mx = fmaxf(mx, __shfl_down(mx, off, 64));
    if (lane == 0) sm[wid] = mx;
    __syncthreads();
    if (tid == 0) bc = fmaxf(fmaxf(sm[0], sm[1]), fmaxf(sm[2], sm[3]));
    __syncthreads();
    float m = bc;
    float e[8], s = 0.f;
    #pragma unroll
    for (int r = 0; r < 8; ++r) { e[r] = __expf(v[r] - m); s += e[r]; }
    #pragma unroll
    for (int off = 32; off >= 1; off >>= 1) s += __shfl_down(s, off, 64);
    __syncthreads();
    if (lane == 0) sm[wid] = s;
    __syncthreads();
    if (tid == 0) bc = (sm[0] + sm[1]) + (sm[2] + sm[3]);
    __syncthreads();
    float inv = 1.0f / bc;
    #pragma unroll
    for (int r = 0; r < 8; ++r) p[b * LL + tid + r * 256] = e[r] * inv;
}

// K3a: partial[b,jc,d] = sum over 128 j of p[b,j]*inp[b,j,d]; 256 blocks (16 b x 16 jc)
__global__ void k3a_partial(const float* __restrict__ inp, const float* __restrict__ p,
                            float* __restrict__ partial) {
    int blk = blockIdx.x;
    int b = blk >> 4, jc = blk & 15;
    int t = threadIdx.x;                          // t = d
    const float* pb = p + b * LL + jc * 128;
    const float* ib = inp + ((size_t)(b * LL + jc * 128)) * DD + t;
    float acc = 0.f;
    #pragma unroll 4
    for (int j = 0; j < 128; ++j) acc += pb[j] * ib[(size_t)j * DD];
    partial[(size_t)blk * DD + t] = acc;
}

// K3b: out_vec[b,d] = sum over jc of partial[b,jc,d]
__global__ void k3b_reduce(const float* __restrict__ partial, float* __restrict__ out_vec) {
    int b = blockIdx.x;
    int t = threadIdx.x;
    float acc = 0.f;
    #pragma unroll
    for (int jc = 0; jc < 16; ++jc) acc += partial[((size_t)(b * 16 + jc)) * DD + t];
    out_vec[b * DD + t] = acc;
}

// K4: broadcast writer. d_out = [out (B*L*D)] ++ [attn (B*L*L)], both fp32.
// out[b,i,d] = out_vec[b,d]; attn[b,i,j] = p[b,j]. Sources are L2-resident.
__global__ void k4_write(const float4* __restrict__ outv4, const float4* __restrict__ p4,
                         float4* __restrict__ dst) {
    const size_t OUT4 = (size_t)BB * LL * DD / 4;      // 2,097,152
    const size_t TOT4 = OUT4 + (size_t)BB * LL * LL / 4; // 18,874,368
    size_t stride = (size_t)gridDim.x * blockDim.x;
    for (size_t i = blockIdx.x * (size_t)blockDim.x + threadIdx.x; i < TOT4; i += stride) {
        float4 v;
        if (i < OUT4) {
            size_t b  = i >> 17;        // / (L*D/4)
            size_t d4 = i & 63;         // % (D/4)
            v = outv4[(b << 6) + d4];
        } else {
            size_t k  = i - OUT4;
            size_t b  = k >> 20;        // / (L*L/4)
            size_t j4 = k & 511;        // % (L/4)
            v = p4[(b << 9) + j4];
        }
        dst[i] = v;
    }
}

extern "C" void kernel_launch(void* const* d_in, const int* in_sizes, int n_in,
                              void* d_out, int out_size, void* d_ws, size_t ws_size,
                              hipStream_t stream) {
    const float* inp = (const float*)d_in[0];
    const float* vw  = (const float*)d_in[1];   // [1, 2D]: wq then wk
    float* out = (float*)d_out;
    float* ws  = (float*)d_ws;

    float* sk      = ws;            // B*L        = 32768 floats
    float* p       = ws + 32768;    // B*L        = 32768 floats
    float* partial = ws + 65536;    // B*16*D     = 65536 floats
    float* out_vec = ws + 131072;   // B*D        = 4096 floats

    k1_sk      <<<8192, 256, 0, stream>>>(inp, vw + DD, sk);
    k2_softmax <<<BB,   256, 0, stream>>>(sk, p);
    k3a_partial<<<256,  256, 0, stream>>>(inp, p, partial);
    k3b_reduce <<<BB,   256, 0, stream>>>(partial, out_vec);
    k4_write   <<<2048, 256, 0, stream>>>((const float4*)out_vec, (const float4*)p,
                                          (float4*)out);
}

// Round 3
// 78.916 us; speedup vs baseline: 1.0199x; 1.0199x over previous
//
#include <hip/hip_runtime.h>

#define BB 16
#define LL 2048
#define DD 256
#define CH 32            // rows per K3a chunk
#define NCH (LL / CH)    // 64 chunks per batch

typedef float vf4 __attribute__((ext_vector_type(4)));  // true vector type: nt-store OK

// K1: sk[row] = dot(inp[row,:], wk)  — one wave (64 lanes) per row, float4/lane
__global__ void k1_sk(const float* __restrict__ inp, const float* __restrict__ wk,
                      float* __restrict__ sk) {
    int tid  = threadIdx.x;
    int wid  = tid >> 6, lane = tid & 63;
    int row  = blockIdx.x * 4 + wid;              // 8192 blocks * 4 waves = 32768 rows
    const float4 a = *reinterpret_cast<const float4*>(inp + (size_t)row * DD + lane * 4);
    const float4 w = *reinterpret_cast<const float4*>(wk + lane * 4);
    float dot = a.x * w.x + a.y * w.y + a.z * w.z + a.w * w.w;
    #pragma unroll
    for (int off = 32; off >= 1; off >>= 1) dot += __shfl_down(dot, off, 64);
    if (lane == 0) sk[row] = dot;
}

// K2: per-batch softmax over L values -> p[b,j]
__global__ void k2_softmax(const float* __restrict__ sk, float* __restrict__ p) {
    int b = blockIdx.x;
    int tid = threadIdx.x;
    int lane = tid & 63, wid = tid >> 6;
    const float* skb = sk + b * LL;
    float v[8];
    #pragma unroll
    for (int r = 0; r < 8; ++r) v[r] = skb[tid + r * 256];
    float mx = v[0];
    #pragma unroll
    for (int r = 1; r < 8; ++r) mx = fmaxf(mx, v[r]);
    __shared__ float sm[4];
    __shared__ float bc;
    #pragma unroll
    for (int off = 32; off >= 1; off >>= 1) mx = fmaxf(mx, __shfl_down(mx, off, 64));
    if (lane == 0) sm[wid] = mx;
    __syncthreads();
    if (tid == 0) bc = fmaxf(fmaxf(sm[0], sm[1]), fmaxf(sm[2], sm[3]));
    __syncthreads();
    float m = bc;
    float e[8], s = 0.f;
    #pragma unroll
    for (int r = 0; r < 8; ++r) { e[r] = __expf(v[r] - m); s += e[r]; }
    #pragma unroll
    for (int off = 32; off >= 1; off >>= 1) s += __shfl_down(s, off, 64);
    __syncthreads();
    if (lane == 0) sm[wid] = s;
    __syncthreads();
    if (tid == 0) bc = (sm[0] + sm[1]) + (sm[2] + sm[3]);
    __syncthreads();
    float inv = 1.0f / bc;
    #pragma unroll
    for (int r = 0; r < 8; ++r) p[b * LL + tid + r * 256] = e[r] * inv;
}

// K3a: partial[b,jc,d] = sum over CH rows of p[b,j]*inp[b,j,d]; 1024 blocks (16 b x 64 jc)
__global__ void k3a_partial(const float* __restrict__ inp, const float* __restrict__ p,
                            float* __restrict__ partial) {
    int blk = blockIdx.x;
    int b = blk >> 6, jc = blk & 63;
    int t = threadIdx.x;                          // t = d
    const float* pb = p + b * LL + jc * CH;
    const float* ib = inp + ((size_t)(b * LL + jc * CH)) * DD + t;
    float acc = 0.f;
    #pragma unroll 8
    for (int j = 0; j < CH; ++j) acc += pb[j] * ib[(size_t)j * DD];
    partial[(size_t)blk * DD + t] = acc;
}

// K3b: out_vec[b,d] = sum over NCH chunks of partial[b,jc,d]
__global__ void k3b_reduce(const float* __restrict__ partial, float* __restrict__ out_vec) {
    int b = blockIdx.x;
    int t = threadIdx.x;
    float acc = 0.f;
    #pragma unroll 8
    for (int jc = 0; jc < NCH; ++jc) acc += partial[((size_t)(b * NCH + jc)) * DD + t];
    out_vec[b * DD + t] = acc;
}

// K4: broadcast writer. d_out = [out (B*L*D)] ++ [attn (B*L*L)], both fp32.
// out[b,i,d] = out_vec[b,d]; attn[b,i,j] = p[b,j]. Sources are L2-resident.
// Non-temporal stores: the 288 MB stream has zero reuse — keep L2 for p/out_vec.
__global__ void k4_write(const vf4* __restrict__ outv4, const vf4* __restrict__ p4,
                         vf4* __restrict__ dst) {
    const size_t OUT4 = (size_t)BB * LL * DD / 4;        // 2,097,152
    const size_t TOT4 = OUT4 + (size_t)BB * LL * LL / 4; // 18,874,368
    size_t stride = (size_t)gridDim.x * blockDim.x;
    for (size_t i = blockIdx.x * (size_t)blockDim.x + threadIdx.x; i < TOT4; i += stride) {
        vf4 v;
        if (i < OUT4) {
            size_t b  = i >> 17;        // / (L*D/4)
            size_t d4 = i & 63;         // % (D/4)
            v = outv4[(b << 6) + d4];
        } else {
            size_t k  = i - OUT4;
            size_t b  = k >> 20;        // / (L*L/4)
            size_t j4 = k & 511;        // % (L/4)
            v = p4[(b << 9) + j4];
        }
        __builtin_nontemporal_store(v, &dst[i]);
    }
}

extern "C" void kernel_launch(void* const* d_in, const int* in_sizes, int n_in,
                              void* d_out, int out_size, void* d_ws, size_t ws_size,
                              hipStream_t stream) {
    const float* inp = (const float*)d_in[0];
    const float* vw  = (const float*)d_in[1];   // [1, 2D]: wq then wk
    float* out = (float*)d_out;
    float* ws  = (float*)d_ws;

    float* sk      = ws;             // B*L          = 32768 floats
    float* p       = ws + 32768;     // B*L          = 32768 floats
    float* partial = ws + 65536;     // B*NCH*D      = 262144 floats
    float* out_vec = ws + 327680;    // B*D          = 4096 floats

    k1_sk      <<<8192, 256, 0, stream>>>(inp, vw + DD, sk);
    k2_softmax <<<BB,   256, 0, stream>>>(sk, p);
    k3a_partial<<<BB * NCH, 256, 0, stream>>>(inp, p, partial);
    k3b_reduce <<<BB,   256, 0, stream>>>(partial, out_vec);
    k4_write   <<<2048, 256, 0, stream>>>((const vf4*)out_vec, (const vf4*)p,
                                          (vf4*)out);
}